// Round 14
// baseline (174.593 us; speedup 1.0000x reference)
//
#include <hip/hip_runtime.h>
#include <stdint.h>

// IDXST(4096x4096): y[r][k] = sum_n x[r][n] sin(pi*n*(2k+1)/8192).
// R17c: identical resubmit of R17 (two prior attempts died with
// infrastructure UnresponsiveContainer errors at FIRST MESSAGE — before any
// kernel code executed; audited kernel for deadlock/OOB/vmcnt hazards: none).
// R17: R15's quad-closed grid (256 blocks x 512 thr, combine fused into the
// epilogue) with A MOVED OUT OF LDS. R15/R16 lesson: the per-CU LDS window
// (128KB reads + 48KB writes per K-tile ~ 2070cyc) is a VOLUME bound on the
// shared LDS pipe — TLP can't add LDS BW (R16), schedule surgery can't
// either (R7-R14). A's share is 64KB reads + 32KB writes. A-fragments are
// row-contiguous (lane(lr,kq) reads A[row][k0+kq*8..+7]; a wave = 16 rows x
// 64B segments) -> load A DIRECTLY global->registers, consume-then-reload:
// av[i] for tile t+1 is loaded right after av[i]'s last MFMA of tile t
// (compiler tracks the register deps and emits the vmcnt waits).
// LDS keeps only B (16KB/K-tile, double-buffered, 32KB total). Per K-tile:
// ONE barrier + ONE counted vmcnt(2) (drains the 2 B-stage gload_lds, issued
// first; the 8 av reloads stay in flight, consumed next tile via compiler
// waits). U: 32 single-phase K-tiles; P then Q: 16 each.
// B strip-gather (mirror strips staged in reversed row order) and the
// register fold epilogue are R15-verified and unchanged. prep unchanged.
// ws (44 MB): xo 16 | xee 8 | xeo 8 | Bo 8 | Bp 2 | Bq 2.

#define NN 4096

typedef __attribute__((ext_vector_type(8))) short short8;
typedef __attribute__((ext_vector_type(4))) float f32x4;

__device__ __forceinline__ unsigned short f2bf(float f) {
  unsigned int u = __float_as_uint(f);
  u += 0x7fffu + ((u >> 16) & 1u);
  return (unsigned short)(u >> 16);
}

__device__ __forceinline__ void async_load16(const void* g, void* lds) {
  __builtin_amdgcn_global_load_lds(
      (const __attribute__((address_space(1))) unsigned int*)g,
      (__attribute__((address_space(3))) unsigned int*)lds, 16, 0, 0);
}

#define NXS (NN * NN / 8)        // 2M x-split threads (8 floats each)
#define NBO (2048 * 2048 / 4)    // 1M Bo threads
#define NBP (1024 * 1024 / 4)    // 256K Bp threads (Bq same)

// prep: xo[r][m]=x[r][2m+1]; xee[r][t]=x[r][4t]; xeo[r][t]=x[r][4t+2];
// Bo[c][m]=sin(pi(2m+1)(2c+1)/8192); Bp[c][t]=sin(pi*t*(2c+1)/2048);
// Bq[c][t]=sin(pi(2t+1)(2c+1)/4096)
__global__ void prep_kernel(const float* __restrict__ x,
                            unsigned short* __restrict__ xo,
                            unsigned short* __restrict__ xee,
                            unsigned short* __restrict__ xeo,
                            unsigned short* __restrict__ Bo,
                            unsigned short* __restrict__ Bp,
                            unsigned short* __restrict__ Bq) {
  int gi = blockIdx.x * blockDim.x + threadIdx.x;
  if (gi < NXS) {
    int g = gi & 511;            // 8-float group in row
    int r = gi >> 9;
    const float4* src = (const float4*)(x + (size_t)r * NN + g * 8);
    float4 v0 = src[0], v1 = src[1];    // n = 8g+0..3, 8g+4..7
    ushort4 ov;                          // odd n -> m = 4g..4g+3
    ov.x = f2bf(v0.y); ov.y = f2bf(v0.w); ov.z = f2bf(v1.y); ov.w = f2bf(v1.w);
    *(ushort4*)&xo[(size_t)r * 2048 + g * 4] = ov;
    unsigned int ee = ((unsigned)f2bf(v1.x) << 16) | f2bf(v0.x);  // t=2g,2g+1
    *(unsigned int*)&xee[(size_t)r * 1024 + g * 2] = ee;
    unsigned int eo = ((unsigned)f2bf(v1.z) << 16) | f2bf(v0.z);
    *(unsigned int*)&xeo[(size_t)r * 1024 + g * 2] = eo;
  } else if (gi < NXS + NBO) {
    int i = gi - NXS;
    int m0 = (i & 511) * 4;
    int c = i >> 9;
    unsigned int tw = 2u * (unsigned)c + 1u;
    const float sc = 3.14159265358979323846f / 8192.0f;
    ushort4 o; unsigned int ph;
    ph = ((unsigned)(2 * (m0 + 0) + 1) * tw) & 16383u; o.x = f2bf(__sinf((float)ph * sc));
    ph = ((unsigned)(2 * (m0 + 1) + 1) * tw) & 16383u; o.y = f2bf(__sinf((float)ph * sc));
    ph = ((unsigned)(2 * (m0 + 2) + 1) * tw) & 16383u; o.z = f2bf(__sinf((float)ph * sc));
    ph = ((unsigned)(2 * (m0 + 3) + 1) * tw) & 16383u; o.w = f2bf(__sinf((float)ph * sc));
    *(ushort4*)&Bo[(size_t)c * 2048 + m0] = o;
  } else if (gi < NXS + NBO + NBP) {
    int i = gi - NXS - NBO;
    int t0 = (i & 255) * 4;
    int c = i >> 8;
    unsigned int tw = 2u * (unsigned)c + 1u;
    const float sc = 3.14159265358979323846f / 2048.0f;
    ushort4 o; unsigned int ph;
    ph = ((unsigned)(t0 + 0) * tw) & 4095u; o.x = f2bf(__sinf((float)ph * sc));
    ph = ((unsigned)(t0 + 1) * tw) & 4095u; o.y = f2bf(__sinf((float)ph * sc));
    ph = ((unsigned)(t0 + 2) * tw) & 4095u; o.z = f2bf(__sinf((float)ph * sc));
    ph = ((unsigned)(t0 + 3) * tw) & 4095u; o.w = f2bf(__sinf((float)ph * sc));
    *(ushort4*)&Bp[(size_t)c * 1024 + t0] = o;
  } else {
    int i = gi - NXS - NBO - NBP;
    int t0 = (i & 255) * 4;
    int c = i >> 8;
    unsigned int tw = 2u * (unsigned)c + 1u;
    const float sc = 3.14159265358979323846f / 4096.0f;
    ushort4 o; unsigned int ph;
    ph = ((unsigned)(2 * (t0 + 0) + 1) * tw) & 8191u; o.x = f2bf(__sinf((float)ph * sc));
    ph = ((unsigned)(2 * (t0 + 1) + 1) * tw) & 8191u; o.y = f2bf(__sinf((float)ph * sc));
    ph = ((unsigned)(2 * (t0 + 2) + 1) * tw) & 8191u; o.z = f2bf(__sinf((float)ph * sc));
    ph = ((unsigned)(2 * (t0 + 3) + 1) * tw) & 8191u; o.w = f2bf(__sinf((float)ph * sc));
    *(ushort4*)&Bq[(size_t)c * 1024 + t0] = o;
  }
}

// ---- LDS (ushort indices): B only, 32 KiB. buf b at b*8192 (16KB).
// U: both 8KB halves used ([S1|S4] then [S2|S3]); P/Q: first 8KB half only.
#define PH_BAR  __builtin_amdgcn_s_barrier()
#define W_VM2   asm volatile("s_waitcnt vmcnt(2)" ::: "memory")
#define W_VM0   asm volatile("s_waitcnt vmcnt(0)" ::: "memory")
#define PRIO1   __builtin_amdgcn_s_setprio(1)
#define PRIO0   __builtin_amdgcn_s_setprio(0)

// Stage one 8KB B chunk (1 load/thread) from a per-thread strip pointer.
#define STAGEB_P(srcp, koff, off)                                               \
    async_load16((srcp) + (koff), &lds[(off) + tid * 8])

// One U K-tile t in buffer b; stages B[t+1] (k-offset kn) into buf b^1 and
// reloads av <- A[t+1] interleaved after each av[i]'s last MFMA.
#define U_TILE(b, kn) do {                                                      \
    { const int _bb = (b) * 8192 + wn * 4096 + lr * 64;                         \
      _Pragma("unroll") for (int _j = 0; _j < 4; ++_j) {                        \
        bv[_j][0] = *(const short8*)&lds[_bb + _j * 1024 + cA0];                \
        bv[_j][1] = *(const short8*)&lds[_bb + _j * 1024 + cA1];                \
      } }                                                                       \
    STAGEB_P(sU0, kn, ((b) ^ 1) * 8192);                                        \
    STAGEB_P(sU1, kn, ((b) ^ 1) * 8192 + 4096);                                 \
    PRIO1;                                                                      \
    _Pragma("unroll") for (int _i = 0; _i < 4; ++_i) {                          \
      _Pragma("unroll") for (int _k = 0; _k < 2; ++_k)                          \
      _Pragma("unroll") for (int _j = 0; _j < 4; ++_j)                          \
        uacc[_i][_j] = __builtin_amdgcn_mfma_f32_16x16x32_bf16(                 \
            av[_i][_k], bv[_j][_k], uacc[_i][_j], 0, 0, 0);                     \
      av[_i][0] = *(const short8*)(aU + (size_t)_i * 32768 + (kn));             \
      av[_i][1] = *(const short8*)(aU + (size_t)_i * 32768 + (kn) + 32);        \
    }                                                                           \
    PRIO0; W_VM2; PH_BAR;                                                       \
  } while (0)

// One P/Q K-tile (64 B-cols in one 8KB chunk); 16 MFMA into ACC.
#define PQ_TILE(ACC, aPtr, sPtr, b, kn) do {                                    \
    { const int _bb = (b) * 8192 + wn * 2048 + lr * 64;                         \
      _Pragma("unroll") for (int _j = 0; _j < 2; ++_j) {                        \
        bvp[_j][0] = *(const short8*)&lds[_bb + _j * 1024 + cA0];               \
        bvp[_j][1] = *(const short8*)&lds[_bb + _j * 1024 + cA1];               \
      } }                                                                       \
    STAGEB_P(sPtr, kn, ((b) ^ 1) * 8192);                                       \
    PRIO1;                                                                      \
    _Pragma("unroll") for (int _i = 0; _i < 4; ++_i) {                          \
      _Pragma("unroll") for (int _k = 0; _k < 2; ++_k)                          \
      _Pragma("unroll") for (int _j = 0; _j < 2; ++_j)                          \
        ACC[_i][_j] = __builtin_amdgcn_mfma_f32_16x16x32_bf16(                  \
            av[_i][_k], bvp[_j][_k], ACC[_i][_j], 0, 0, 0);                     \
      av[_i][0] = *(const short8*)((aPtr) + (size_t)_i * 16384 + (kn));         \
      av[_i][1] = *(const short8*)((aPtr) + (size_t)_i * 16384 + (kn) + 32);    \
    }                                                                           \
    PRIO0; W_VM2; PH_BAR;                                                       \
  } while (0)

__global__ __launch_bounds__(512) void gemm3_kernel(
    const unsigned short* __restrict__ xo,
    const unsigned short* __restrict__ xee,
    const unsigned short* __restrict__ xeo,
    const unsigned short* __restrict__ Bo,
    const unsigned short* __restrict__ Bp,
    const unsigned short* __restrict__ Bq,
    float* __restrict__ out) {
  __shared__ __align__(16) unsigned short lds[16384];   // 32 KiB (B only)

  const int bx = blockIdx.x;           // 256 identical blocks
  const int row0 = (bx & 15) * 256;
  const int c0 = (bx >> 4) * 32;       // quad-group base k'

  const int tid = threadIdx.x;
  const int lane = tid & 63;
  const int wave = tid >> 6;
  const int wm = wave >> 1;            // 0..3 : 64-row strip
  const int wn = wave & 1;             // 0..1 : col-half (strip pair)
  const int lr = lane & 15, kq = lane >> 4;
  const int st_r = tid >> 3;                         // staging row 0..63
  const int st_c = ((tid & 7) ^ (st_r & 7)) * 8;     // pre-swizzled src chunk
  const int cA0 = (kq ^ (lr & 7)) * 8;               // swizzled ds_read chunks
  const int cA1 = ((4 + kq) ^ (lr & 7)) * 8;

  // Per-lane A base pointers (direct global->reg A fragments).
  const int arow = row0 + wm * 64 + lr;
  const unsigned short* aU = xo  + (size_t)arow * 2048 + kq * 8;
  const unsigned short* aP = xee + (size_t)arow * 1024 + kq * 8;
  const unsigned short* aQ = xeo + (size_t)arow * 1024 + kq * 8;

  // Per-thread B staging strip pointers (mirror strips in reversed order).
  const int ru0 = (st_r < 32) ? (c0 + st_r) : (2047 - c0 - (st_r - 32));
  const int ru1 = (st_r < 32) ? (1023 - c0 - st_r) : (1024 + c0 + (st_r - 32));
  const int rpq = (st_r < 32) ? (c0 + st_r) : (1023 - c0 - (st_r - 32));
  const unsigned short* sU0 = Bo + (size_t)ru0 * 2048 + st_c;
  const unsigned short* sU1 = Bo + (size_t)ru1 * 2048 + st_c;
  const unsigned short* sP  = Bp + (size_t)rpq * 1024 + st_c;
  const unsigned short* sQ  = Bq + (size_t)rpq * 1024 + st_c;

  f32x4 uacc[4][4], pacc[4][2], qacc[4][2];
#pragma unroll
  for (int i = 0; i < 4; ++i) {
#pragma unroll
    for (int j = 0; j < 4; ++j) uacc[i][j] = (f32x4){0.f, 0.f, 0.f, 0.f};
#pragma unroll
    for (int j = 0; j < 2; ++j) {
      pacc[i][j] = (f32x4){0.f, 0.f, 0.f, 0.f};
      qacc[i][j] = (f32x4){0.f, 0.f, 0.f, 0.f};
    }
  }
  short8 av[4][2], bv[4][2], bvp[2][2];

  // ================= U segment: 256x128, K=2048, 32 K-tiles ================
  // Prologue: B[0] -> buf0; av <- A[0]; drain; barrier.
  STAGEB_P(sU0, 0, 0);
  STAGEB_P(sU1, 0, 4096);
#pragma unroll
  for (int i = 0; i < 4; ++i) {
    av[i][0] = *(const short8*)(aU + (size_t)i * 32768);
    av[i][1] = *(const short8*)(aU + (size_t)i * 32768 + 32);
  }
  W_VM0; PH_BAR;

  for (int it = 0; it < 15; ++it) {      // tiles 0..29
    const int t64 = it << 7;
    U_TILE(0, t64 + 64);
    U_TILE(1, t64 + 128);
  }
  U_TILE(0, 1984);                       // tile 30, stages/reloads tile 31
  { // peel tile 31 (buf1): MFMAs only
    const int _bb = 8192 + wn * 4096 + lr * 64;
#pragma unroll
    for (int _j = 0; _j < 4; ++_j) {
      bv[_j][0] = *(const short8*)&lds[_bb + _j * 1024 + cA0];
      bv[_j][1] = *(const short8*)&lds[_bb + _j * 1024 + cA1];
    }
    PRIO1;
#pragma unroll
    for (int _i = 0; _i < 4; ++_i)
#pragma unroll
      for (int _k = 0; _k < 2; ++_k)
#pragma unroll
        for (int _j = 0; _j < 4; ++_j)
          uacc[_i][_j] = __builtin_amdgcn_mfma_f32_16x16x32_bf16(
              av[_i][_k], bv[_j][_k], uacc[_i][_j], 0, 0, 0);
    PRIO0;
  }

  // ================= P segment: 256x64, K=1024, 16 K-tiles =================
  // buf0 last read at U tile 30 (sealed by its barrier) -> safe to restage.
  STAGEB_P(sP, 0, 0);
#pragma unroll
  for (int i = 0; i < 4; ++i) {
    av[i][0] = *(const short8*)(aP + (size_t)i * 16384);
    av[i][1] = *(const short8*)(aP + (size_t)i * 16384 + 32);
  }
  W_VM0; PH_BAR;
  for (int it = 0; it < 7; ++it) {       // tiles 0..13
    const int t64 = it << 7;
    PQ_TILE(pacc, aP, sP, 0, t64 + 64);
    PQ_TILE(pacc, aP, sP, 1, t64 + 128);
  }
  PQ_TILE(pacc, aP, sP, 0, 960);         // tile 14, stages/reloads tile 15
  { // peel tile 15 (buf1)
    const int _bb = 8192 + wn * 2048 + lr * 64;
#pragma unroll
    for (int _j = 0; _j < 2; ++_j) {
      bvp[_j][0] = *(const short8*)&lds[_bb + _j * 1024 + cA0];
      bvp[_j][1] = *(const short8*)&lds[_bb + _j * 1024 + cA1];
    }
    PRIO1;
#pragma unroll
    for (int _i = 0; _i < 4; ++_i)
#pragma unroll
      for (int _k = 0; _k < 2; ++_k)
#pragma unroll
        for (int _j = 0; _j < 2; ++_j)
          pacc[_i][_j] = __builtin_amdgcn_mfma_f32_16x16x32_bf16(
              av[_i][_k], bvp[_j][_k], pacc[_i][_j], 0, 0, 0);
    PRIO0;
  }

  // ================= Q segment: 256x64, K=1024, 16 K-tiles =================
  STAGEB_P(sQ, 0, 0);
#pragma unroll
  for (int i = 0; i < 4; ++i) {
    av[i][0] = *(const short8*)(aQ + (size_t)i * 16384);
    av[i][1] = *(const short8*)(aQ + (size_t)i * 16384 + 32);
  }
  W_VM0; PH_BAR;
  for (int it = 0; it < 7; ++it) {       // tiles 0..13
    const int t64 = it << 7;
    PQ_TILE(qacc, aQ, sQ, 0, t64 + 64);
    PQ_TILE(qacc, aQ, sQ, 1, t64 + 128);
  }
  PQ_TILE(qacc, aQ, sQ, 0, 960);         // tile 14
  { // peel tile 15 (buf1)
    const int _bb = 8192 + wn * 2048 + lr * 64;
#pragma unroll
    for (int _j = 0; _j < 2; ++_j) {
      bvp[_j][0] = *(const short8*)&lds[_bb + _j * 1024 + cA0];
      bvp[_j][1] = *(const short8*)&lds[_bb + _j * 1024 + cA1];
    }
    PRIO1;
#pragma unroll
    for (int _i = 0; _i < 4; ++_i)
#pragma unroll
      for (int _k = 0; _k < 2; ++_k)
#pragma unroll
        for (int _j = 0; _j < 2; ++_j)
          qacc[_i][_j] = __builtin_amdgcn_mfma_f32_16x16x32_bf16(
              av[_i][_k], bvp[_j][_k], qacc[_i][_j], 0, 0, 0);
    PRIO0;
  }

  // ===================== epilogue: full two-level fold =====================
  // wn=0: u1=u[k'], u4=u[2047-k'], p/q at k'.  wn=1: u1=u[1023-k'],
  // u4=u[1024+k'], p/q at 1023-k'.  k' = c0+cs, cs = j*16+lr.
#pragma unroll
  for (int i = 0; i < 4; ++i)
#pragma unroll
    for (int j = 0; j < 2; ++j)
#pragma unroll
      for (int rr = 0; rr < 4; ++rr) {
        const int r_out = row0 + wm * 64 + i * 16 + kq * 4 + rr;
        float* orow = out + (size_t)r_out * NN;
        const int cs = j * 16 + lr;
        const float u1 = uacc[i][j][rr];
        const float u4 = uacc[i][j + 2][rr];
        const float pa = pacc[i][j][rr];
        const float qa = qacc[i][j][rr];
        const float v1 = pa + qa;
        const float v2 = qa - pa;
        if (wn == 0) {
          orow[c0 + cs]        = v1 + u1;   // y[k']
          orow[4095 - c0 - cs] = u1 - v1;   // y[4095-k']
          orow[2047 - c0 - cs] = v2 + u4;   // y[2047-k']
          orow[2048 + c0 + cs] = u4 - v2;   // y[2048+k']
        } else {
          orow[1023 - c0 - cs] = v1 + u1;   // y[1023-k']
          orow[3072 + c0 + cs] = u1 - v1;   // y[3072+k']
          orow[1024 + c0 + cs] = v2 + u4;   // y[1024+k']
          orow[3071 - c0 - cs] = u4 - v2;   // y[3071-k']
        }
      }
}

extern "C" void kernel_launch(void* const* d_in, const int* in_sizes, int n_in,
                              void* d_out, int out_size, void* d_ws, size_t ws_size,
                              hipStream_t stream) {
  const float* x = (const float*)d_in[0];
  float* out = (float*)d_out;
  unsigned short* xo  = (unsigned short*)d_ws;            // 16 MB
  unsigned short* xee = xo + (size_t)NN * 2048;           // 8 MB
  unsigned short* xeo = xee + (size_t)NN * 1024;          // 8 MB
  unsigned short* Bo  = xeo + (size_t)NN * 1024;          // 8 MB
  unsigned short* Bp  = Bo + (size_t)2048 * 2048;         // 2 MB
  unsigned short* Bq  = Bp + (size_t)1024 * 1024;         // 2 MB -> 44 MB total

  int prep_threads = NXS + NBO + 2 * NBP;
  prep_kernel<<<prep_threads / 256, 256, 0, stream>>>(x, xo, xee, xeo, Bo, Bp, Bq);

  gemm3_kernel<<<256, 512, 0, stream>>>(xo, xee, xeo, Bo, Bp, Bq, out);
}

// Round 15
// 78.280 us; speedup vs baseline: 2.2304x; 2.2304x over previous
//
#include <hip/hip_runtime.h>
#include <stdint.h>

// IDXST(4096x4096): y[r][k] = sum_n x[r][n] sin(pi*n*(2k+1)/8192).
// R18: R15 (quad-closed grid, combine fused into epilogue, 79.6us verified)
// with LEADING BARRIERS REMOVED — each phase is now {reads+stage -> lgkm ->
// MFMA -> BAR}. The trailing barrier carries every hazard: a stage into
// region R in phase k needs all reads of R sealed by phase k-1's trailing
// barrier (A dbuf: staged region last read >=2 phases earlier; B single-buf:
// last read the phase before its restage); staged-data visibility is carried
// by W_VM0/W_VM5 + the following trailing barrier (unchanged positions).
// The leading barrier only forced 8-wave lockstep — the exact serializer of
// the LDS window vs MFMA window (R11-R14 accounting ~450cyc/phase fixed).
// Removing it lets waves skew so one wave's ds_reads run under another's
// MFMAs (m114 overlap) at unchanged LDS volume. U: 7->4 barriers/K-tile.
// R17 post-mortem: direct global->reg A was 2.4x WORSE (158us, MfmaUtil
// 12.5%) — gload_lds staging IS the latency-hiding machinery; reverted.
// ws (44 MB): xo 16 | xee 8 | xeo 8 | Bo 8 | Bp 2 | Bq 2. prep unchanged.

#define NN 4096

typedef __attribute__((ext_vector_type(8))) short short8;
typedef __attribute__((ext_vector_type(4))) float f32x4;

__device__ __forceinline__ unsigned short f2bf(float f) {
  unsigned int u = __float_as_uint(f);
  u += 0x7fffu + ((u >> 16) & 1u);
  return (unsigned short)(u >> 16);
}

__device__ __forceinline__ void async_load16(const void* g, void* lds) {
  __builtin_amdgcn_global_load_lds(
      (const __attribute__((address_space(1))) unsigned int*)g,
      (__attribute__((address_space(3))) unsigned int*)lds, 16, 0, 0);
}

#define NXS (NN * NN / 8)        // 2M x-split threads (8 floats each)
#define NBO (2048 * 2048 / 4)    // 1M Bo threads
#define NBP (1024 * 1024 / 4)    // 256K Bp threads (Bq same)

// prep: xo[r][m]=x[r][2m+1]; xee[r][t]=x[r][4t]; xeo[r][t]=x[r][4t+2];
// Bo[c][m]=sin(pi(2m+1)(2c+1)/8192); Bp[c][t]=sin(pi*t*(2c+1)/2048);
// Bq[c][t]=sin(pi(2t+1)(2c+1)/4096)
__global__ void prep_kernel(const float* __restrict__ x,
                            unsigned short* __restrict__ xo,
                            unsigned short* __restrict__ xee,
                            unsigned short* __restrict__ xeo,
                            unsigned short* __restrict__ Bo,
                            unsigned short* __restrict__ Bp,
                            unsigned short* __restrict__ Bq) {
  int gi = blockIdx.x * blockDim.x + threadIdx.x;
  if (gi < NXS) {
    int g = gi & 511;            // 8-float group in row
    int r = gi >> 9;
    const float4* src = (const float4*)(x + (size_t)r * NN + g * 8);
    float4 v0 = src[0], v1 = src[1];    // n = 8g+0..3, 8g+4..7
    ushort4 ov;                          // odd n -> m = 4g..4g+3
    ov.x = f2bf(v0.y); ov.y = f2bf(v0.w); ov.z = f2bf(v1.y); ov.w = f2bf(v1.w);
    *(ushort4*)&xo[(size_t)r * 2048 + g * 4] = ov;
    unsigned int ee = ((unsigned)f2bf(v1.x) << 16) | f2bf(v0.x);  // t=2g,2g+1
    *(unsigned int*)&xee[(size_t)r * 1024 + g * 2] = ee;
    unsigned int eo = ((unsigned)f2bf(v1.z) << 16) | f2bf(v0.z);
    *(unsigned int*)&xeo[(size_t)r * 1024 + g * 2] = eo;
  } else if (gi < NXS + NBO) {
    int i = gi - NXS;
    int m0 = (i & 511) * 4;
    int c = i >> 9;
    unsigned int tw = 2u * (unsigned)c + 1u;
    const float sc = 3.14159265358979323846f / 8192.0f;
    ushort4 o; unsigned int ph;
    ph = ((unsigned)(2 * (m0 + 0) + 1) * tw) & 16383u; o.x = f2bf(__sinf((float)ph * sc));
    ph = ((unsigned)(2 * (m0 + 1) + 1) * tw) & 16383u; o.y = f2bf(__sinf((float)ph * sc));
    ph = ((unsigned)(2 * (m0 + 2) + 1) * tw) & 16383u; o.z = f2bf(__sinf((float)ph * sc));
    ph = ((unsigned)(2 * (m0 + 3) + 1) * tw) & 16383u; o.w = f2bf(__sinf((float)ph * sc));
    *(ushort4*)&Bo[(size_t)c * 2048 + m0] = o;
  } else if (gi < NXS + NBO + NBP) {
    int i = gi - NXS - NBO;
    int t0 = (i & 255) * 4;
    int c = i >> 8;
    unsigned int tw = 2u * (unsigned)c + 1u;
    const float sc = 3.14159265358979323846f / 2048.0f;
    ushort4 o; unsigned int ph;
    ph = ((unsigned)(t0 + 0) * tw) & 4095u; o.x = f2bf(__sinf((float)ph * sc));
    ph = ((unsigned)(t0 + 1) * tw) & 4095u; o.y = f2bf(__sinf((float)ph * sc));
    ph = ((unsigned)(t0 + 2) * tw) & 4095u; o.z = f2bf(__sinf((float)ph * sc));
    ph = ((unsigned)(t0 + 3) * tw) & 4095u; o.w = f2bf(__sinf((float)ph * sc));
    *(ushort4*)&Bp[(size_t)c * 1024 + t0] = o;
  } else {
    int i = gi - NXS - NBO - NBP;
    int t0 = (i & 255) * 4;
    int c = i >> 8;
    unsigned int tw = 2u * (unsigned)c + 1u;
    const float sc = 3.14159265358979323846f / 4096.0f;
    ushort4 o; unsigned int ph;
    ph = ((unsigned)(2 * (t0 + 0) + 1) * tw) & 8191u; o.x = f2bf(__sinf((float)ph * sc));
    ph = ((unsigned)(2 * (t0 + 1) + 1) * tw) & 8191u; o.y = f2bf(__sinf((float)ph * sc));
    ph = ((unsigned)(2 * (t0 + 2) + 1) * tw) & 8191u; o.z = f2bf(__sinf((float)ph * sc));
    ph = ((unsigned)(2 * (t0 + 3) + 1) * tw) & 8191u; o.w = f2bf(__sinf((float)ph * sc));
    *(ushort4*)&Bq[(size_t)c * 1024 + t0] = o;
  }
}

// ---- LDS layout (ushort indices) ----------------------------------------
// Ap buf0 [0,16384) | Ap buf1 [16384,32768) | Aq buf0 [32768,49152) |
// Aq buf1 [49152,65536) | B half0 [65536,69632) | B half1 [69632,73728).
// U segment uses Ap bufs + both B halves (128 cols); PQ uses all.
#define PH_BAR  __builtin_amdgcn_s_barrier()
#define W_LGKM0 asm volatile("s_waitcnt lgkmcnt(0)" ::: "memory")
#define W_VM5   asm volatile("s_waitcnt vmcnt(5)" ::: "memory")
#define W_VM0   asm volatile("s_waitcnt vmcnt(0)" ::: "memory")
#define PRIO1   __builtin_amdgcn_s_setprio(1)
#define PRIO0   __builtin_amdgcn_s_setprio(0)

// Stage a 128-row x 64-k A half-tile (16KB, 2 loads/thread). Linear LDS dest;
// source chunk pre-swizzled by the chunk^(row&7) involution the reads apply.
#define STAGEA_G(Abase, Kc, prow0, koff, off) do {                              \
    const unsigned short* _s =                                                  \
        (Abase) + (size_t)((prow0) + st_r) * (Kc) + (koff) + st_c;              \
    async_load16(_s, &lds[(off) + tid * 8]);                                    \
    async_load16(_s + (size_t)64 * (Kc), &lds[(off) + 4096 + tid * 8]);         \
  } while (0)

// Stage one 64-col B chunk (8KB, 1 load/thread) from a precomputed per-thread
// row pointer (strip-gather with mirror strips in reversed order).
#define STAGEB_P(srcp, koff, off)                                               \
    async_load16((srcp) + (koff), &lds[(off) + tid * 8])

// A-frags for row-half mh of A buffer b at LDS base `base`: 4 ds_read_b128.
#define LOADA_G(base, b, mh) do {                                               \
    const int _ab = (base) + (b) * 16384 + wm * 4096 + (mh) * 2048 + lr * 64;   \
    _Pragma("unroll") for (int _i = 0; _i < 2; ++_i) {                          \
      av[(mh) * 2 + _i][0] = *(const short8*)&lds[_ab + _i * 1024 + cA0];       \
      av[(mh) * 2 + _i][1] = *(const short8*)&lds[_ab + _i * 1024 + cA1];       \
    }                                                                           \
  } while (0)

// U B-frags for col-half nh (32 of the wave's 64 cols): 4 ds_read_b128.
#define LOADB_U(SET, nh) do {                                                   \
    const int _bb = 65536 + wn * 4096 + (nh) * 2048 + lr * 64;                  \
    _Pragma("unroll") for (int _j = 0; _j < 2; ++_j) {                          \
      SET[_j][0] = *(const short8*)&lds[_bb + _j * 1024 + cA0];                 \
      SET[_j][1] = *(const short8*)&lds[_bb + _j * 1024 + cA1];                 \
    }                                                                           \
  } while (0)

// PQ B-frags (wave's 32 cols of a 64-col B chunk at `base`): 4 ds_read_b128.
#define LOADB_PQ(SET, base) do {                                                \
    const int _bb = (base) + wn * 2048 + lr * 64;                               \
    _Pragma("unroll") for (int _j = 0; _j < 2; ++_j) {                          \
      SET[_j][0] = *(const short8*)&lds[_bb + _j * 1024 + cA0];                 \
      SET[_j][1] = *(const short8*)&lds[_bb + _j * 1024 + cA1];                 \
    }                                                                           \
  } while (0)

// U quadrant (32x32) x K=64: 8 MFMA into uacc.
#define MMAQ_U(BS, mh, nh) do {                                                 \
    _Pragma("unroll") for (int _k = 0; _k < 2; ++_k)                            \
    _Pragma("unroll") for (int _i = 0; _i < 2; ++_i)                            \
    _Pragma("unroll") for (int _j = 0; _j < 2; ++_j)                            \
      uacc[(mh) * 2 + _i][(nh) * 2 + _j] =                                      \
          __builtin_amdgcn_mfma_f32_16x16x32_bf16(                              \
              av[(mh) * 2 + _i][_k], BS[_j][_k],                                \
              uacc[(mh) * 2 + _i][(nh) * 2 + _j], 0, 0, 0);                     \
  } while (0)

// P/Q half (32 rows x 32 cols) x K=64: 8 MFMA into ACC.
#define MMAQ_PQ(ACC, BS, mh) do {                                               \
    _Pragma("unroll") for (int _k = 0; _k < 2; ++_k)                            \
    _Pragma("unroll") for (int _i = 0; _i < 2; ++_i)                            \
    _Pragma("unroll") for (int _j = 0; _j < 2; ++_j)                            \
      ACC[(mh) * 2 + _i][_j] =                                                  \
          __builtin_amdgcn_mfma_f32_16x16x32_bf16(                              \
              av[(mh) * 2 + _i][_k], BS[_j][_k],                                \
              ACC[(mh) * 2 + _i][_j], 0, 0, 0);                                 \
  } while (0)

__global__ __launch_bounds__(512) void gemm3_kernel(
    const unsigned short* __restrict__ xo,
    const unsigned short* __restrict__ xee,
    const unsigned short* __restrict__ xeo,
    const unsigned short* __restrict__ Bo,
    const unsigned short* __restrict__ Bp,
    const unsigned short* __restrict__ Bq,
    float* __restrict__ out) {
  __shared__ __align__(16) unsigned short lds[73728];   // 144 KiB

  const int bx = blockIdx.x;           // 256 identical blocks
  const int row0 = (bx & 15) * 256;
  const int c0 = (bx >> 4) * 32;       // quad-group base k'

  const int tid = threadIdx.x;
  const int lane = tid & 63;
  const int wave = tid >> 6;
  const int wm = wave >> 1;            // 0..3 : 64-row strip
  const int wn = wave & 1;             // 0..1 : col-half (strip pair)
  const int lr = lane & 15, kq = lane >> 4;
  const int st_r = tid >> 3;                         // staging row 0..63
  const int st_c = ((tid & 7) ^ (st_r & 7)) * 8;     // pre-swizzled src chunk
  const int cA0 = (kq ^ (lr & 7)) * 8;               // swizzled ds_read chunks
  const int cA1 = ((4 + kq) ^ (lr & 7)) * 8;

  // Per-thread B staging row pointers (strip-gather; mirrors reversed).
  const int ru0 = (st_r < 32) ? (c0 + st_r) : (2047 - c0 - (st_r - 32));
  const int ru1 = (st_r < 32) ? (1023 - c0 - st_r) : (1024 + c0 + (st_r - 32));
  const int rpq = (st_r < 32) ? (c0 + st_r) : (1023 - c0 - (st_r - 32));
  const unsigned short* sBo0 = Bo + (size_t)ru0 * 2048 + st_c;
  const unsigned short* sBo1 = Bo + (size_t)ru1 * 2048 + st_c;
  const unsigned short* sBp  = Bp + (size_t)rpq * 1024 + st_c;
  const unsigned short* sBq  = Bq + (size_t)rpq * 1024 + st_c;

  f32x4 uacc[4][4], pacc[4][2], qacc[4][2];
#pragma unroll
  for (int i = 0; i < 4; ++i) {
#pragma unroll
    for (int j = 0; j < 4; ++j) uacc[i][j] = (f32x4){0.f, 0.f, 0.f, 0.f};
#pragma unroll
    for (int j = 0; j < 2; ++j) {
      pacc[i][j] = (f32x4){0.f, 0.f, 0.f, 0.f};
      qacc[i][j] = (f32x4){0.f, 0.f, 0.f, 0.f};
    }
  }
  short8 av[4][2], bv0[2][2], bv1[2][2];

  // ================= U segment: 256x128, K=2048, 32 K-tiles ================
  STAGEA_G(xo, 2048, row0,       0, 0);
  STAGEA_G(xo, 2048, row0 + 128, 0, 8192);
  STAGEB_P(sBo0, 0, 65536);
  STAGEB_P(sBo1, 0, 69632);
  W_VM0; PH_BAR;

  for (int it = 0; it < 15; ++it) {
    const int t64 = it << 7;
    // tile t (buf0)
    LOADA_G(0, 0, 0); LOADB_U(bv0, 0);
    STAGEA_G(xo, 2048, row0, t64 + 64, 16384);
    W_LGKM0; PRIO1; MMAQ_U(bv0, 0, 0); PRIO0; PH_BAR;
    LOADB_U(bv1, 1);
    STAGEA_G(xo, 2048, row0 + 128, t64 + 64, 24576);
    W_LGKM0; PRIO1; MMAQ_U(bv1, 0, 1); PRIO0; PH_BAR;
    LOADA_G(0, 0, 1);
    STAGEB_P(sBo0, t64 + 64, 65536);
    STAGEB_P(sBo1, t64 + 64, 69632);
    W_LGKM0; PRIO1; MMAQ_U(bv1, 1, 1); PRIO0; PH_BAR;
    PRIO1; MMAQ_U(bv0, 1, 0); PRIO0; W_VM0; PH_BAR;
    // tile t+1 (buf1)
    LOADA_G(0, 1, 0); LOADB_U(bv0, 0);
    STAGEA_G(xo, 2048, row0, t64 + 128, 0);
    W_LGKM0; PRIO1; MMAQ_U(bv0, 0, 0); PRIO0; PH_BAR;
    LOADB_U(bv1, 1);
    STAGEA_G(xo, 2048, row0 + 128, t64 + 128, 8192);
    W_LGKM0; PRIO1; MMAQ_U(bv1, 0, 1); PRIO0; PH_BAR;
    LOADA_G(0, 1, 1);
    STAGEB_P(sBo0, t64 + 128, 65536);
    STAGEB_P(sBo1, t64 + 128, 69632);
    W_LGKM0; PRIO1; MMAQ_U(bv1, 1, 1); PRIO0; PH_BAR;
    PRIO1; MMAQ_U(bv0, 1, 0); PRIO0; W_VM0; PH_BAR;
  }
  { // peel tiles 30 (buf0) + 31 (buf1)
    LOADA_G(0, 0, 0); LOADB_U(bv0, 0);
    STAGEA_G(xo, 2048, row0, 1984, 16384);
    W_LGKM0; PRIO1; MMAQ_U(bv0, 0, 0); PRIO0; PH_BAR;
    LOADB_U(bv1, 1);
    STAGEA_G(xo, 2048, row0 + 128, 1984, 24576);
    W_LGKM0; PRIO1; MMAQ_U(bv1, 0, 1); PRIO0; PH_BAR;
    LOADA_G(0, 0, 1);
    STAGEB_P(sBo0, 1984, 65536);
    STAGEB_P(sBo1, 1984, 69632);
    W_LGKM0; PRIO1; MMAQ_U(bv1, 1, 1); PRIO0; PH_BAR;
    PRIO1; MMAQ_U(bv0, 1, 0); PRIO0; W_VM0; PH_BAR;
    LOADA_G(0, 1, 0); LOADB_U(bv0, 0);
    W_LGKM0; PRIO1; MMAQ_U(bv0, 0, 0); PRIO0;
    LOADB_U(bv1, 1);
    W_LGKM0; PRIO1; MMAQ_U(bv1, 0, 1); PRIO0;
    LOADA_G(0, 1, 1);
    W_LGKM0; PRIO1; MMAQ_U(bv1, 1, 1); MMAQ_U(bv0, 1, 0); PRIO0;
  }

  // ============== PQ segment: fused P,Q loops, K=1024, 16 K-tiles ==========
  PH_BAR;   // all waves done reading U's B region before Bp lands there
  STAGEA_G(xee, 1024, row0,       0, 0);
  STAGEA_G(xee, 1024, row0 + 128, 0, 8192);
  STAGEB_P(sBp, 0, 65536);
  STAGEA_G(xeo, 1024, row0,       0, 32768);
  STAGEA_G(xeo, 1024, row0 + 128, 0, 40960);
  STAGEB_P(sBq, 0, 69632);
  W_VM5; PH_BAR;   // drains Ap[0]+Bp[0]; leaves Aq[0](4)+Bq[0](1) in flight

// One PQ K-tile t in buffer b; stages tile t+1 (koff kn) into buffer b^1.
#define PQ_TILE(b, kn) do {                                                     \
    LOADA_G(0, b, 0); LOADB_PQ(bv0, 65536);                                     \
    STAGEA_G(xee, 1024, row0, kn, ((b) ^ 1) * 16384);                           \
    W_LGKM0; PRIO1; MMAQ_PQ(pacc, bv0, 0); PRIO0; PH_BAR;                       \
    LOADA_G(0, b, 1);                                                           \
    STAGEA_G(xee, 1024, row0 + 128, kn, ((b) ^ 1) * 16384 + 8192);              \
    STAGEB_P(sBp, kn, 65536);                                                   \
    W_LGKM0; PRIO1; MMAQ_PQ(pacc, bv0, 1); PRIO0; W_VM5; PH_BAR;                \
    LOADA_G(32768, b, 0); LOADB_PQ(bv1, 69632);                                 \
    STAGEA_G(xeo, 1024, row0, kn, 32768 + ((b) ^ 1) * 16384);                   \
    W_LGKM0; PRIO1; MMAQ_PQ(qacc, bv1, 0); PRIO0; PH_BAR;                       \
    LOADA_G(32768, b, 1);                                                       \
    STAGEA_G(xeo, 1024, row0 + 128, kn, 32768 + ((b) ^ 1) * 16384 + 8192);      \
    STAGEB_P(sBq, kn, 69632);                                                   \
    W_LGKM0; PRIO1; MMAQ_PQ(qacc, bv1, 1); PRIO0; W_VM5; PH_BAR;                \
  } while (0)

  for (int it = 0; it < 7; ++it) {       // tiles 0..13
    const int t64 = it << 7;
    PQ_TILE(0, t64 + 64);
    PQ_TILE(1, t64 + 128);
  }
  PQ_TILE(0, 960);                       // tile 14, stages tile 15
  { // peel tile 15 (buf1)
    LOADA_G(0, 1, 0); LOADB_PQ(bv0, 65536);
    W_LGKM0; PRIO1; MMAQ_PQ(pacc, bv0, 0); PRIO0;
    LOADA_G(0, 1, 1);
    W_LGKM0; PRIO1; MMAQ_PQ(pacc, bv0, 1); PRIO0; W_VM0; PH_BAR;
    LOADA_G(32768, 1, 0); LOADB_PQ(bv1, 69632);
    W_LGKM0; PRIO1; MMAQ_PQ(qacc, bv1, 0); PRIO0;
    LOADA_G(32768, 1, 1);
    W_LGKM0; PRIO1; MMAQ_PQ(qacc, bv1, 1); PRIO0;
  }
#undef PQ_TILE

  // ===================== epilogue: full two-level fold =====================
  // wn=0: u1=u[k'], u4=u[2047-k'], p/q at k'.  wn=1: u1=u[1023-k'],
  // u4=u[1024+k'], p/q at 1023-k'.  k' = c0+cs, cs = j*16+lr.
#pragma unroll
  for (int i = 0; i < 4; ++i)
#pragma unroll
    for (int j = 0; j < 2; ++j)
#pragma unroll
      for (int rr = 0; rr < 4; ++rr) {
        const int r_out = row0 + wm * 64 + i * 16 + kq * 4 + rr;
        float* orow = out + (size_t)r_out * NN;
        const int cs = j * 16 + lr;
        const float u1 = uacc[i][j][rr];
        const float u4 = uacc[i][j + 2][rr];
        const float pa = pacc[i][j][rr];
        const float qa = qacc[i][j][rr];
        const float v1 = pa + qa;
        const float v2 = qa - pa;
        if (wn == 0) {
          orow[c0 + cs]        = v1 + u1;   // y[k']
          orow[4095 - c0 - cs] = u1 - v1;   // y[4095-k']
          orow[2047 - c0 - cs] = v2 + u4;   // y[2047-k']
          orow[2048 + c0 + cs] = u4 - v2;   // y[2048+k']
        } else {
          orow[1023 - c0 - cs] = v1 + u1;   // y[1023-k']
          orow[3072 + c0 + cs] = u1 - v1;   // y[3072+k']
          orow[1024 + c0 + cs] = v2 + u4;   // y[1024+k']
          orow[3071 - c0 - cs] = u4 - v2;   // y[3071-k']
        }
      }
}

extern "C" void kernel_launch(void* const* d_in, const int* in_sizes, int n_in,
                              void* d_out, int out_size, void* d_ws, size_t ws_size,
                              hipStream_t stream) {
  const float* x = (const float*)d_in[0];
  float* out = (float*)d_out;
  unsigned short* xo  = (unsigned short*)d_ws;            // 16 MB
  unsigned short* xee = xo + (size_t)NN * 2048;           // 8 MB
  unsigned short* xeo = xee + (size_t)NN * 1024;          // 8 MB
  unsigned short* Bo  = xeo + (size_t)NN * 1024;          // 8 MB
  unsigned short* Bp  = Bo + (size_t)2048 * 2048;         // 2 MB
  unsigned short* Bq  = Bp + (size_t)1024 * 1024;         // 2 MB -> 44 MB total

  int prep_threads = NXS + NBO + 2 * NBP;
  prep_kernel<<<prep_threads / 256, 256, 0, stream>>>(x, xo, xee, xeo, Bo, Bp, Bq);

  gemm3_kernel<<<256, 512, 0, stream>>>(xo, xee, xeo, Bo, Bp, Bq, out);
}

// Round 16
// 76.534 us; speedup vs baseline: 2.2812x; 1.0228x over previous
//
#include <hip/hip_runtime.h>
#include <stdint.h>

// IDXST(4096x4096): y[r][k] = sum_n x[r][n] sin(pi*n*(2k+1)/8192).
// R19: R18 (quad-closed grid, fold-in-epilogue, trailing-barrier phases,
// 78.3us) restructured to TRI-BUFFERED, COUNTED-VMCNT, 1-BARRIER-PER-K-TILE
// (the T4 "never drain to 0" discipline). R18 accounting: K-tile 3150cyc,
// MFMA 32% busy, LDS reads 41B/cyc (48% of ceiling) — BOTH pipes idle;
// residue = wait states (per-tile W_VM0 drain ~400-800cyc after issue, plus
// 4x W_LGKM0 full drains serializing read-completion vs MFMA issue).
// Now: A 3x32KB + B 3x16KB = 144KB. Tile t stages tile t+2; tile-end counted
// vmcnt (6 for U, 5 for P/Q = loads/tile) drains exactly tile t+1, leaving
// t+2 in flight a FULL K-tile (~2500cyc) before its drain — covers HBM-miss.
// Staged region last read two tiles ago (sealed 2 barriers back) -> ALL
// intra-tile barriers and ALL lgkm full-drains deleted; compiler emits
// fine-grained lgkmcnt per fragment (m97). Segment boundaries pipelined:
// U30/31 stage P0/P1, P14/15 stage Q0/Q1; single W_VM0 at Q14.
// FIFO ledger: prologue 12 -> VM6; U0..U29 VM6; U30,U31 VM5; P0..P15 VM5;
// Q0..Q13 VM5; Q14 VM0; Q15 none.
// ws (44 MB): xo 16 | xee 8 | xeo 8 | Bo 8 | Bp 2 | Bq 2. prep unchanged.

#define NN 4096

typedef __attribute__((ext_vector_type(8))) short short8;
typedef __attribute__((ext_vector_type(4))) float f32x4;

__device__ __forceinline__ unsigned short f2bf(float f) {
  unsigned int u = __float_as_uint(f);
  u += 0x7fffu + ((u >> 16) & 1u);
  return (unsigned short)(u >> 16);
}

__device__ __forceinline__ void async_load16(const void* g, void* lds) {
  __builtin_amdgcn_global_load_lds(
      (const __attribute__((address_space(1))) unsigned int*)g,
      (__attribute__((address_space(3))) unsigned int*)lds, 16, 0, 0);
}

#define NXS (NN * NN / 8)        // 2M x-split threads (8 floats each)
#define NBO (2048 * 2048 / 4)    // 1M Bo threads
#define NBP (1024 * 1024 / 4)    // 256K Bp threads (Bq same)

// prep: xo[r][m]=x[r][2m+1]; xee[r][t]=x[r][4t]; xeo[r][t]=x[r][4t+2];
// Bo[c][m]=sin(pi(2m+1)(2c+1)/8192); Bp[c][t]=sin(pi*t*(2c+1)/2048);
// Bq[c][t]=sin(pi(2t+1)(2c+1)/4096)
__global__ void prep_kernel(const float* __restrict__ x,
                            unsigned short* __restrict__ xo,
                            unsigned short* __restrict__ xee,
                            unsigned short* __restrict__ xeo,
                            unsigned short* __restrict__ Bo,
                            unsigned short* __restrict__ Bp,
                            unsigned short* __restrict__ Bq) {
  int gi = blockIdx.x * blockDim.x + threadIdx.x;
  if (gi < NXS) {
    int g = gi & 511;            // 8-float group in row
    int r = gi >> 9;
    const float4* src = (const float4*)(x + (size_t)r * NN + g * 8);
    float4 v0 = src[0], v1 = src[1];    // n = 8g+0..3, 8g+4..7
    ushort4 ov;                          // odd n -> m = 4g..4g+3
    ov.x = f2bf(v0.y); ov.y = f2bf(v0.w); ov.z = f2bf(v1.y); ov.w = f2bf(v1.w);
    *(ushort4*)&xo[(size_t)r * 2048 + g * 4] = ov;
    unsigned int ee = ((unsigned)f2bf(v1.x) << 16) | f2bf(v0.x);  // t=2g,2g+1
    *(unsigned int*)&xee[(size_t)r * 1024 + g * 2] = ee;
    unsigned int eo = ((unsigned)f2bf(v1.z) << 16) | f2bf(v0.z);
    *(unsigned int*)&xeo[(size_t)r * 1024 + g * 2] = eo;
  } else if (gi < NXS + NBO) {
    int i = gi - NXS;
    int m0 = (i & 511) * 4;
    int c = i >> 9;
    unsigned int tw = 2u * (unsigned)c + 1u;
    const float sc = 3.14159265358979323846f / 8192.0f;
    ushort4 o; unsigned int ph;
    ph = ((unsigned)(2 * (m0 + 0) + 1) * tw) & 16383u; o.x = f2bf(__sinf((float)ph * sc));
    ph = ((unsigned)(2 * (m0 + 1) + 1) * tw) & 16383u; o.y = f2bf(__sinf((float)ph * sc));
    ph = ((unsigned)(2 * (m0 + 2) + 1) * tw) & 16383u; o.z = f2bf(__sinf((float)ph * sc));
    ph = ((unsigned)(2 * (m0 + 3) + 1) * tw) & 16383u; o.w = f2bf(__sinf((float)ph * sc));
    *(ushort4*)&Bo[(size_t)c * 2048 + m0] = o;
  } else if (gi < NXS + NBO + NBP) {
    int i = gi - NXS - NBO;
    int t0 = (i & 255) * 4;
    int c = i >> 8;
    unsigned int tw = 2u * (unsigned)c + 1u;
    const float sc = 3.14159265358979323846f / 2048.0f;
    ushort4 o; unsigned int ph;
    ph = ((unsigned)(t0 + 0) * tw) & 4095u; o.x = f2bf(__sinf((float)ph * sc));
    ph = ((unsigned)(t0 + 1) * tw) & 4095u; o.y = f2bf(__sinf((float)ph * sc));
    ph = ((unsigned)(t0 + 2) * tw) & 4095u; o.z = f2bf(__sinf((float)ph * sc));
    ph = ((unsigned)(t0 + 3) * tw) & 4095u; o.w = f2bf(__sinf((float)ph * sc));
    *(ushort4*)&Bp[(size_t)c * 1024 + t0] = o;
  } else {
    int i = gi - NXS - NBO - NBP;
    int t0 = (i & 255) * 4;
    int c = i >> 8;
    unsigned int tw = 2u * (unsigned)c + 1u;
    const float sc = 3.14159265358979323846f / 4096.0f;
    ushort4 o; unsigned int ph;
    ph = ((unsigned)(2 * (t0 + 0) + 1) * tw) & 8191u; o.x = f2bf(__sinf((float)ph * sc));
    ph = ((unsigned)(2 * (t0 + 1) + 1) * tw) & 8191u; o.y = f2bf(__sinf((float)ph * sc));
    ph = ((unsigned)(2 * (t0 + 2) + 1) * tw) & 8191u; o.z = f2bf(__sinf((float)ph * sc));
    ph = ((unsigned)(2 * (t0 + 3) + 1) * tw) & 8191u; o.w = f2bf(__sinf((float)ph * sc));
    *(ushort4*)&Bq[(size_t)c * 1024 + t0] = o;
  }
}

// ---- LDS layout (ushort indices), 144 KiB -------------------------------
// A bufs: AB0=0, AB1=16384, AB2=32768 (32KB each: two 16KB halves).
// B bufs: BB0=49152, BB1=57344, BB2=65536 (16KB each; U uses both 8KB
// chunks, P/Q use the first 8KB).
#define AB0 0
#define AB1 16384
#define AB2 32768
#define BB0 49152
#define BB1 57344
#define BB2 65536

#define PH_BAR  __builtin_amdgcn_s_barrier()
#define W_VM6   asm volatile("s_waitcnt vmcnt(6)" ::: "memory")
#define W_VM5   asm volatile("s_waitcnt vmcnt(5)" ::: "memory")
#define W_VM0   asm volatile("s_waitcnt vmcnt(0)" ::: "memory")
#define PRIO1   __builtin_amdgcn_s_setprio(1)
#define PRIO0   __builtin_amdgcn_s_setprio(0)

// Stage a 128-row x 64-k A half-tile (16KB, 2 loads/thread). Linear LDS dest;
// source chunk pre-swizzled by the chunk^(row&7) involution the reads apply.
#define STAGEA_G(Abase, Kc, prow0, koff, off) do {                              \
    const unsigned short* _s =                                                  \
        (Abase) + (size_t)((prow0) + st_r) * (Kc) + (koff) + st_c;              \
    async_load16(_s, &lds[(off) + tid * 8]);                                    \
    async_load16(_s + (size_t)64 * (Kc), &lds[(off) + 4096 + tid * 8]);         \
  } while (0)

// Stage one 64-row B chunk (8KB, 1 load/thread) from a per-thread strip ptr.
#define STAGEB_P(srcp, koff, off)                                               \
    async_load16((srcp) + (koff), &lds[(off) + tid * 8])

// A-frags for row-half mh from A-buf base ab: 4 ds_read_b128.
#define LOADA3(ab, mh) do {                                                     \
    const int _ab = (ab) + wm * 4096 + (mh) * 2048 + lr * 64;                   \
    _Pragma("unroll") for (int _i = 0; _i < 2; ++_i) {                          \
      av[(mh) * 2 + _i][0] = *(const short8*)&lds[_ab + _i * 1024 + cA0];       \
      av[(mh) * 2 + _i][1] = *(const short8*)&lds[_ab + _i * 1024 + cA1];       \
    }                                                                           \
  } while (0)

// U B-frags for col-half nh from B-buf base bb: 4 ds_read_b128.
#define LOADBU3(SET, bb, nh) do {                                               \
    const int _bb = (bb) + wn * 4096 + (nh) * 2048 + lr * 64;                   \
    _Pragma("unroll") for (int _j = 0; _j < 2; ++_j) {                          \
      SET[_j][0] = *(const short8*)&lds[_bb + _j * 1024 + cA0];                 \
      SET[_j][1] = *(const short8*)&lds[_bb + _j * 1024 + cA1];                 \
    }                                                                           \
  } while (0)

// PQ B-frags from B-buf base bb (wave's 32 of 64 cols): 4 ds_read_b128.
#define LOADBP3(SET, bb) do {                                                   \
    const int _bb = (bb) + wn * 2048 + lr * 64;                                 \
    _Pragma("unroll") for (int _j = 0; _j < 2; ++_j) {                          \
      SET[_j][0] = *(const short8*)&lds[_bb + _j * 1024 + cA0];                 \
      SET[_j][1] = *(const short8*)&lds[_bb + _j * 1024 + cA1];                 \
    }                                                                           \
  } while (0)

// U quadrant (32x32) x K=64: 8 MFMA into uacc.
#define MMAQ_U(BS, mh, nh) do {                                                 \
    _Pragma("unroll") for (int _k = 0; _k < 2; ++_k)                            \
    _Pragma("unroll") for (int _i = 0; _i < 2; ++_i)                            \
    _Pragma("unroll") for (int _j = 0; _j < 2; ++_j)                            \
      uacc[(mh) * 2 + _i][(nh) * 2 + _j] =                                      \
          __builtin_amdgcn_mfma_f32_16x16x32_bf16(                              \
              av[(mh) * 2 + _i][_k], BS[_j][_k],                                \
              uacc[(mh) * 2 + _i][(nh) * 2 + _j], 0, 0, 0);                     \
  } while (0)

// P/Q half (32 rows x 32 cols) x K=64: 8 MFMA into ACC.
#define MMAQ_PQ(ACC, BS, mh) do {                                               \
    _Pragma("unroll") for (int _k = 0; _k < 2; ++_k)                            \
    _Pragma("unroll") for (int _i = 0; _i < 2; ++_i)                            \
    _Pragma("unroll") for (int _j = 0; _j < 2; ++_j)                            \
      ACC[(mh) * 2 + _i][_j] =                                                  \
          __builtin_amdgcn_mfma_f32_16x16x32_bf16(                              \
              av[(mh) * 2 + _i][_k], BS[_j][_k],                                \
              ACC[(mh) * 2 + _i][_j], 0, 0, 0);                                 \
  } while (0)

// Per-tile composites --------------------------------------------------------
#define U_CORE(ab, bb)                                                          \
    LOADA3(ab, 0); LOADA3(ab, 1);                                               \
    LOADBU3(bv0, bb, 0); LOADBU3(bv1, bb, 1)

#define U_MMA                                                                   \
    PRIO1; MMAQ_U(bv0, 0, 0); MMAQ_U(bv1, 0, 1);                                \
    MMAQ_U(bv1, 1, 1); MMAQ_U(bv0, 1, 0); PRIO0

#define STG_U(an, bn, kn)                                                       \
    STAGEA_G(xo, 2048, row0, kn, an);                                           \
    STAGEA_G(xo, 2048, row0 + 128, kn, (an) + 8192);                            \
    STAGEB_P(sBo0, kn, bn);                                                     \
    STAGEB_P(sBo1, kn, (bn) + 4096)

#define STG_P(an, bn, kn)                                                       \
    STAGEA_G(xee, 1024, row0, kn, an);                                          \
    STAGEA_G(xee, 1024, row0 + 128, kn, (an) + 8192);                           \
    STAGEB_P(sBp, kn, bn)

#define STG_Q(an, bn, kn)                                                       \
    STAGEA_G(xeo, 1024, row0, kn, an);                                          \
    STAGEA_G(xeo, 1024, row0 + 128, kn, (an) + 8192);                           \
    STAGEB_P(sBq, kn, bn)

#define PQ_CORE(ab, bb)                                                         \
    LOADA3(ab, 0); LOADA3(ab, 1); LOADBP3(bvp, bb)

#define PQ_MMA(ACC)                                                             \
    PRIO1; MMAQ_PQ(ACC, bvp, 0); MMAQ_PQ(ACC, bvp, 1); PRIO0

__global__ __launch_bounds__(512) void gemm3_kernel(
    const unsigned short* __restrict__ xo,
    const unsigned short* __restrict__ xee,
    const unsigned short* __restrict__ xeo,
    const unsigned short* __restrict__ Bo,
    const unsigned short* __restrict__ Bp,
    const unsigned short* __restrict__ Bq,
    float* __restrict__ out) {
  __shared__ __align__(16) unsigned short lds[73728];   // 144 KiB

  const int bx = blockIdx.x;           // 256 identical blocks
  const int row0 = (bx & 15) * 256;
  const int c0 = (bx >> 4) * 32;       // quad-group base k'

  const int tid = threadIdx.x;
  const int lane = tid & 63;
  const int wave = tid >> 6;
  const int wm = wave >> 1;            // 0..3 : 64-row strip
  const int wn = wave & 1;             // 0..1 : col-half (strip pair)
  const int lr = lane & 15, kq = lane >> 4;
  const int st_r = tid >> 3;                         // staging row 0..63
  const int st_c = ((tid & 7) ^ (st_r & 7)) * 8;     // pre-swizzled src chunk
  const int cA0 = (kq ^ (lr & 7)) * 8;               // swizzled ds_read chunks
  const int cA1 = ((4 + kq) ^ (lr & 7)) * 8;

  // Per-thread B staging row pointers (strip-gather; mirrors reversed).
  const int ru0 = (st_r < 32) ? (c0 + st_r) : (2047 - c0 - (st_r - 32));
  const int ru1 = (st_r < 32) ? (1023 - c0 - st_r) : (1024 + c0 + (st_r - 32));
  const int rpq = (st_r < 32) ? (c0 + st_r) : (1023 - c0 - (st_r - 32));
  const unsigned short* sBo0 = Bo + (size_t)ru0 * 2048 + st_c;
  const unsigned short* sBo1 = Bo + (size_t)ru1 * 2048 + st_c;
  const unsigned short* sBp  = Bp + (size_t)rpq * 1024 + st_c;
  const unsigned short* sBq  = Bq + (size_t)rpq * 1024 + st_c;

  f32x4 uacc[4][4], pacc[4][2], qacc[4][2];
#pragma unroll
  for (int i = 0; i < 4; ++i) {
#pragma unroll
    for (int j = 0; j < 4; ++j) uacc[i][j] = (f32x4){0.f, 0.f, 0.f, 0.f};
#pragma unroll
    for (int j = 0; j < 2; ++j) {
      pacc[i][j] = (f32x4){0.f, 0.f, 0.f, 0.f};
      qacc[i][j] = (f32x4){0.f, 0.f, 0.f, 0.f};
    }
  }
  short8 av[4][2], bv0[2][2], bv1[2][2], bvp[2][2];

  // Prologue: stage U0 -> buf0, U1 -> buf1 (12 loads); drain U0, keep U1.
  STG_U(AB0, BB0, 0);
  STG_U(AB1, BB1, 64);
  W_VM6; PH_BAR;

  // ================= U segment: 32 K-tiles, tri-buffered ===================
  for (int it = 0; it < 10; ++it) {      // tiles 0..29
    const int kb = it * 192;
    U_CORE(AB0, BB0); STG_U(AB2, BB2, kb + 128); U_MMA; W_VM6; PH_BAR;
    U_CORE(AB1, BB1); STG_U(AB0, BB0, kb + 192); U_MMA; W_VM6; PH_BAR;
    U_CORE(AB2, BB2); STG_U(AB1, BB1, kb + 256); U_MMA; W_VM6; PH_BAR;
  }
  // U30 (buf0): stage P0 -> buf2 (drain U31's 6, leave P0's 5)
  U_CORE(AB0, BB0); STG_P(AB2, BB2, 0); U_MMA; W_VM5; PH_BAR;
  // U31 (buf1): stage P1 -> buf0 (drain P0's 5, leave P1's 5)
  U_CORE(AB1, BB1); STG_P(AB0, BB0, 64); U_MMA; W_VM5; PH_BAR;

  // ================= P segment: 16 K-tiles (P t in buf (t+2)%3) ============
  for (int it = 0; it < 4; ++it) {       // tiles 0..11
    const int kb = it * 192;
    PQ_CORE(AB2, BB2); STG_P(AB1, BB1, kb + 128); PQ_MMA(pacc); W_VM5; PH_BAR;
    PQ_CORE(AB0, BB0); STG_P(AB2, BB2, kb + 192); PQ_MMA(pacc); W_VM5; PH_BAR;
    PQ_CORE(AB1, BB1); STG_P(AB0, BB0, kb + 256); PQ_MMA(pacc); W_VM5; PH_BAR;
  }
  PQ_CORE(AB2, BB2); STG_P(AB1, BB1, 896); PQ_MMA(pacc); W_VM5; PH_BAR;  // P12
  PQ_CORE(AB0, BB0); STG_P(AB2, BB2, 960); PQ_MMA(pacc); W_VM5; PH_BAR;  // P13
  PQ_CORE(AB1, BB1); STG_Q(AB0, BB0, 0);   PQ_MMA(pacc); W_VM5; PH_BAR;  // P14
  PQ_CORE(AB2, BB2); STG_Q(AB1, BB1, 64);  PQ_MMA(pacc); W_VM5; PH_BAR;  // P15

  // ================= Q segment: 16 K-tiles (Q t in buf t%3) ================
  for (int it = 0; it < 4; ++it) {       // tiles 0..11
    const int kb = it * 192;
    PQ_CORE(AB0, BB0); STG_Q(AB2, BB2, kb + 128); PQ_MMA(qacc); W_VM5; PH_BAR;
    PQ_CORE(AB1, BB1); STG_Q(AB0, BB0, kb + 192); PQ_MMA(qacc); W_VM5; PH_BAR;
    PQ_CORE(AB2, BB2); STG_Q(AB1, BB1, kb + 256); PQ_MMA(qacc); W_VM5; PH_BAR;
  }
  PQ_CORE(AB0, BB0); STG_Q(AB2, BB2, 896); PQ_MMA(qacc); W_VM5; PH_BAR;  // Q12
  PQ_CORE(AB1, BB1); STG_Q(AB0, BB0, 960); PQ_MMA(qacc); W_VM5; PH_BAR;  // Q13
  PQ_CORE(AB2, BB2); PQ_MMA(qacc); W_VM0; PH_BAR;                        // Q14
  PQ_CORE(AB0, BB0); PQ_MMA(qacc);                                       // Q15

  // ===================== epilogue: full two-level fold =====================
  // wn=0: u1=u[k'], u4=u[2047-k'], p/q at k'.  wn=1: u1=u[1023-k'],
  // u4=u[1024+k'], p/q at 1023-k'.  k' = c0+cs, cs = j*16+lr.
#pragma unroll
  for (int i = 0; i < 4; ++i)
#pragma unroll
    for (int j = 0; j < 2; ++j)
#pragma unroll
      for (int rr = 0; rr < 4; ++rr) {
        const int r_out = row0 + wm * 64 + i * 16 + kq * 4 + rr;
        float* orow = out + (size_t)r_out * NN;
        const int cs = j * 16 + lr;
        const float u1 = uacc[i][j][rr];
        const float u4 = uacc[i][j + 2][rr];
        const float pa = pacc[i][j][rr];
        const float qa = qacc[i][j][rr];
        const float v1 = pa + qa;
        const float v2 = qa - pa;
        if (wn == 0) {
          orow[c0 + cs]        = v1 + u1;   // y[k']
          orow[4095 - c0 - cs] = u1 - v1;   // y[4095-k']
          orow[2047 - c0 - cs] = v2 + u4;   // y[2047-k']
          orow[2048 + c0 + cs] = u4 - v2;   // y[2048+k']
        } else {
          orow[1023 - c0 - cs] = v1 + u1;   // y[1023-k']
          orow[3072 + c0 + cs] = u1 - v1;   // y[3072+k']
          orow[1024 + c0 + cs] = v2 + u4;   // y[1024+k']
          orow[3071 - c0 - cs] = u4 - v2;   // y[3071-k']
        }
      }
}

extern "C" void kernel_launch(void* const* d_in, const int* in_sizes, int n_in,
                              void* d_out, int out_size, void* d_ws, size_t ws_size,
                              hipStream_t stream) {
  const float* x = (const float*)d_in[0];
  float* out = (float*)d_out;
  unsigned short* xo  = (unsigned short*)d_ws;            // 16 MB
  unsigned short* xee = xo + (size_t)NN * 2048;           // 8 MB
  unsigned short* xeo = xee + (size_t)NN * 1024;          // 8 MB
  unsigned short* Bo  = xeo + (size_t)NN * 1024;          // 8 MB
  unsigned short* Bp  = Bo + (size_t)2048 * 2048;         // 2 MB
  unsigned short* Bq  = Bp + (size_t)1024 * 1024;         // 2 MB -> 44 MB total

  int prep_threads = NXS + NBO + 2 * NBP;
  prep_kernel<<<prep_threads / 256, 256, 0, stream>>>(x, xo, xee, xeo, Bo, Bp, Bq);

  gemm3_kernel<<<256, 512, 0, stream>>>(xo, xee, xeo, Bo, Bp, Bq, out);
}